// Round 1
// baseline (507.530 us; speedup 1.0000x reference)
//
#include <hip/hip_runtime.h>
#include <cmath>

typedef float2 c32;

__device__ __forceinline__ c32 cmul(c32 a, c32 b){ return make_float2(a.x*b.x - a.y*b.y, a.x*b.y + a.y*b.x); }
__device__ __forceinline__ c32 cadd(c32 a, c32 b){ return make_float2(a.x+b.x, a.y+b.y); }
__device__ __forceinline__ c32 cconj(c32 a){ return make_float2(a.x, -a.y); }

// ---------------- workspace layout ----------------
// float2 region (counts in float2 elements)
#define N_TW20 20
#define N_TW12 12
#define N_TW8  8
#define N_TW6  6
#define N_CY1  (8*6*11)      // (o*6+l)*11+pi
#define N_CY2  (16*3*8*25)   // ((o*3+l)*8+i)*25+pi*5+qi
#define N_XS   (2048*36)     // n*36 + l*l + mi
#define N_XS2  (2048*8*35)   // (n*8+i)*35 + {0,1,10}[l] + mi*(2l+1)+pi

#define O_TW20 0
#define O_TW12 (O_TW20 + N_TW20)
#define O_TW8  (O_TW12 + N_TW12)
#define O_TW6  (O_TW8 + N_TW8)
#define O_CY1  (O_TW6 + N_TW6)
#define O_CY2  (O_CY1 + N_CY1)
#define O_XS   (O_CY2 + N_CY2)
#define O_XS2  (O_XS + N_XS)
#define N_C32_TOTAL (O_XS2 + N_XS2)

// float region (counts in floats), base = after float2 region
#define O_S2D  0
#define N_S2D  (6*20*11)     // (l*20+k)*11+mi   : d^l_{m,0}(beta_in_k)*w_k
#define O_D1   (O_S2D + N_S2D)
#define N_D1   (6*12*121)    // (l*12+k)*121+mi*11+pi : d^l at beta_l1
#define O_SO3D (O_D1 + N_D1)
#define N_SO3D (3*12*25)     // (l*12+k)*25+mi*5+pi : d^l at beta_l1 * w
#define O_D2   (O_SO3D + N_SO3D)
#define N_D2   (3*6*25)      // (l*6+k)*25+mi*5+pi : d^l at beta_l2
#define O_D1S  (O_D2 + N_D2)
#define N_D1S  (6*3*11)      // (l*3+ib)*11+pi : d^l_{p,0}(_b[ib])
#define O_D2S  (O_D1S + N_D1S)
#define N_D2S  (3*3*25)      // (l*3+ib)*25+pi*5+qi
#define O_WINT (O_D2S + N_D2S)
#define N_WINT 6
#define O_FEAT (O_WINT + N_WINT)
#define N_FEAT (2048*16)
#define O_POOL (O_FEAT + N_FEAT)
#define N_POOL 64
#define N_F_TOTAL (O_POOL + N_POOL)

#define DPI 3.14159265358979323846

// ---------------- Wigner-d on device (double, matches ref float64) ----------------
__device__ __forceinline__ double dev_lf(int n){ return lgamma((double)n + 1.0); }

__device__ double dev_wig(int l, int mp, int m, double beta){
    int k0 = max(0, m - mp), k1 = min(l + m, l - mp);
    double c = cos(0.5*beta), s = sin(0.5*beta);
    double lnum = 0.5*(dev_lf(l+mp)+dev_lf(l-mp)+dev_lf(l+m)+dev_lf(l-m));
    double acc = 0.0;
    for (int k = k0; k <= k1; ++k){
        double lg = lnum - dev_lf(l+m-k) - dev_lf(k) - dev_lf(mp-m+k) - dev_lf(l-mp-k);
        double t = exp(lg) * pow(c, (double)(2*l-2*k+m-mp)) * pow(s, (double)(mp-m+2*k));
        acc += ((mp-m+k) & 1) ? -t : t;
    }
    return acc;
}

__device__ double dev_qw(int b, double beta){
    double s = 0.0;
    for (int j = 0; j < b; ++j) s += sin((2.0*j+1.0)*beta)/(2.0*j+1.0);
    return (2.0/b)*sin(beta)*s;
}

// ---------------- setup 1: all weight-independent tables ----------------
__global__ __launch_bounds__(256) void k_setup1(c32* cb, float* fb){
    int gid = blockIdx.x*256 + threadIdx.x;
    if (gid < 20){ double a = -2.0*DPI*gid/20.0; cb[O_TW20+gid] = make_float2((float)cos(a),(float)sin(a)); return; }
    gid -= 20;
    if (gid < 12){ double a =  2.0*DPI*gid/12.0; cb[O_TW12+gid] = make_float2((float)cos(a),(float)sin(a)); return; }
    gid -= 12;
    if (gid < 8){ double a =  2.0*DPI*gid/8.0;  cb[O_TW8 +gid] = make_float2((float)cos(a),(float)sin(a)); return; }
    gid -= 8;
    if (gid < 6){ double a =  2.0*DPI*gid/6.0;  cb[O_TW6 +gid] = make_float2((float)cos(a),(float)sin(a)); return; }
    gid -= 6;
    if (gid < N_S2D){
        int mi = gid%11; int t = gid/11; int k = t%20; int l = t/20;
        float v = 0.f;
        if (mi < 2*l+1){
            double beta = DPI*(2*k+1)/40.0;
            v = (float)(dev_wig(l, mi-l, 0, beta) * dev_qw(10, beta));
        }
        fb[O_S2D+gid] = v; return;
    }
    gid -= N_S2D;
    if (gid < N_D1){
        int pi = gid%11; int t = gid/11; int mi = t%11; t /= 11; int k = t%12; int l = t/12;
        float v = 0.f;
        if (mi < 2*l+1 && pi < 2*l+1){ double beta = DPI*(2*k+1)/24.0; v = (float)dev_wig(l, mi-l, pi-l, beta); }
        fb[O_D1+gid] = v; return;
    }
    gid -= N_D1;
    if (gid < N_SO3D){
        int pi = gid%5; int t = gid/5; int mi = t%5; t /= 5; int k = t%12; int l = t/12;
        float v = 0.f;
        if (mi < 2*l+1 && pi < 2*l+1){ double beta = DPI*(2*k+1)/24.0; v = (float)(dev_wig(l, mi-l, pi-l, beta)*dev_qw(6, beta)); }
        fb[O_SO3D+gid] = v; return;
    }
    gid -= N_SO3D;
    if (gid < N_D2){
        int pi = gid%5; int t = gid/5; int mi = t%5; t /= 5; int k = t%6; int l = t/6;
        float v = 0.f;
        if (mi < 2*l+1 && pi < 2*l+1){ double beta = DPI*(2*k+1)/12.0; v = (float)dev_wig(l, mi-l, pi-l, beta); }
        fb[O_D2+gid] = v; return;
    }
    gid -= N_D2;
    if (gid < N_D1S){
        int pi = gid%11; int t = gid/11; int ib = t%3; int l = t/3;
        float v = 0.f;
        if (pi < 2*l+1){ double beta = (ib+1)*DPI/24.0; v = (float)dev_wig(l, pi-l, 0, beta); }
        fb[O_D1S+gid] = v; return;
    }
    gid -= N_D1S;
    if (gid < N_D2S){
        int qi = gid%5; int t = gid/5; int pi = t%5; t /= 5; int ib = t%3; int l = t/3;
        float v = 0.f;
        if (pi < 2*l+1 && qi < 2*l+1){ double beta = (ib+1)*DPI/24.0; v = (float)dev_wig(l, pi-l, qi-l, beta); }
        fb[O_D2S+gid] = v; return;
    }
    gid -= N_D2S;
    if (gid < 6){ double beta = DPI*(2*gid+1)/12.0; fb[O_WINT+gid] = (float)dev_qw(3, beta); return; }
}

// ---------------- setup 2: conj(Y1)[o][l][pi] ----------------
__global__ __launch_bounds__(256) void k_setup2(c32* cb, const float* fb, const float* __restrict__ w1){
    int gid = blockIdx.x*256 + threadIdx.x;
    if (gid >= 528) return;
    int pi = gid%11; int t = gid/11; int l = t%6; int o = t/6;
    c32 acc = make_float2(0.f,0.f);
    if (pi < 2*l+1){
        int p = pi - l;
        for (int ib = 0; ib < 3; ++ib){
            float d = fb[O_D1S + (l*3+ib)*11 + pi];
            c32 s = make_float2(0.f,0.f);
            for (int ia = 0; ia < 8; ++ia){
                c32 e = cb[O_TW8 + ((p+40)*ia)%8];   // e^{+i p alpha}
                float w = w1[o*24 + ib*8 + ia];
                s.x += w*e.x; s.y += w*e.y;
            }
            acc.x += d*s.x; acc.y += d*s.y;
        }
    }
    cb[O_CY1 + gid] = acc;
}

// ---------------- setup 3: conj(Y2)[o][l][i][pi][qi] ----------------
__global__ __launch_bounds__(256) void k_setup3(c32* cb, const float* fb, const float* __restrict__ w2){
    int gid = blockIdx.x*256 + threadIdx.x;
    if (gid >= 9600) return;
    int qi = gid%5; int t = gid/5; int pi = t%5; t /= 5; int i = t%8; t /= 8; int l = t%3; int o = t/3;
    c32 acc = make_float2(0.f,0.f);
    if (pi < 2*l+1 && qi < 2*l+1){
        int p = pi - l, q = qi - l;
        for (int ib = 0; ib < 3; ++ib){
            float d = fb[O_D2S + (l*3+ib)*25 + pi*5 + qi];
            c32 s = make_float2(0.f,0.f);
            for (int ia = 0; ia < 8; ++ia){
                c32 e8 = cb[O_TW8 + ((p+40)*ia)%8];
                for (int ig = 0; ig < 6; ++ig){
                    c32 e6 = cb[O_TW6 + ((q+6)*ig)%6];
                    c32 ph = cmul(e8, e6);           // e^{+i(p a + q g)}
                    float w = w2[(i*16+o)*144 + ib*48 + ia*6 + ig];
                    s.x += w*ph.x; s.y += w*ph.y;
                }
            }
            acc.x += d*s.x; acc.y += d*s.y;
        }
    }
    cb[O_CY2 + gid] = acc;
}

// ---------------- s2 fft: x[2048,1,20,20] -> XS[n][l^2+mi] ----------------
__global__ __launch_bounds__(64) void k_s2fft(const float* __restrict__ x, const c32* __restrict__ cb,
                                              const float* __restrict__ fb, c32* __restrict__ XS){
    __shared__ float xsh[400];
    __shared__ c32 F1[20][6];
    int n = blockIdx.x, tid = threadIdx.x;
    for (int i = tid; i < 400; i += 64) xsh[i] = x[n*400 + i];
    __syncthreads();
    for (int i = tid; i < 120; i += 64){
        int k = i/6, m = i%6;
        c32 acc = make_float2(0.f,0.f);
        for (int a = 0; a < 20; ++a){
            c32 e = cb[O_TW20 + (m*a)%20];           // e^{-2pi i m a/20}
            float v = xsh[k*20+a];
            acc.x += v*e.x; acc.y += v*e.y;
        }
        F1[k][m] = acc;
    }
    __syncthreads();
    if (tid < 36){
        int l = 0; while ((l+1)*(l+1) <= tid) ++l;
        int mi = tid - l*l; int m = mi - l;
        c32 acc = make_float2(0.f,0.f);
        for (int k = 0; k < 20; ++k){
            float d = fb[O_S2D + (l*20+k)*11 + mi];
            c32 F = (m >= 0) ? F1[k][m] : cconj(F1[k][-m]);
            acc.x += d*F.x; acc.y += d*F.y;
        }
        XS[n*36 + tid] = acc;
    }
}

// ---------------- layer 1 megakernel: per (n,o) ----------------
// z -> S(k,m,p) -> T(k,m,g) -> h(k,a,g)+ReLU -> G(k,ma,mg>=0) -> xs2 (sum over k)
__global__ __launch_bounds__(256) void k_layer1(const c32* __restrict__ cb, const float* __restrict__ fb,
                                                const float* __restrict__ b1, c32* __restrict__ xs2out){
    __shared__ c32 xs_sh[36];
    __shared__ c32 cy1_sh[66];
    __shared__ c32 tw12[12];
    __shared__ c32 zp[286];
    __shared__ c32 Sc[1452];      // [12][11][11]
    __shared__ c32 Tt[1584];      // [12][11][12]
    __shared__ float hh[1728];    // [12][12][12]
    __shared__ c32 Gg[432];       // [12][12][3]
    __shared__ c32 Gs[180];       // [12][5][3]
    int tid = threadIdx.x;
    int n = blockIdx.x >> 3, o = blockIdx.x & 7;
    float bias = b1[o];
    if (tid < 36) xs_sh[tid] = cb[O_XS + n*36 + tid];
    else if (tid >= 64 && tid < 130) cy1_sh[tid-64] = cb[O_CY1 + o*66 + (tid-64)];
    else if (tid >= 192 && tid < 204) tw12[tid-192] = cb[O_TW12 + (tid-192)];
    __syncthreads();
    // zp[l,mi,pi] = (2l+1) * xs[l][mi] * conjY1[l][pi]
    for (int idx = tid; idx < 286; idx += 256){
        int l = 0, base = 0;
        while (idx >= base + (2*l+1)*(2*l+1)){ base += (2*l+1)*(2*l+1); ++l; }
        int w = 2*l+1; int r = idx - base; int mi = r/w, pi = r%w;
        c32 v = cmul(xs_sh[l*l + mi], cy1_sh[l*11 + pi]);
        float f = (float)w;
        zp[idx] = make_float2(f*v.x, f*v.y);
    }
    __syncthreads();
    // Sc[k][m+5][p+5] = sum_l zp * d1
    for (int idx = tid; idx < 1452; idx += 256){
        int k = idx/121, r = idx%121, mi5 = r/11, pi5 = r%11;
        int m = mi5-5, p = pi5-5;
        int lmin = max(abs(m), abs(p));
        c32 acc = make_float2(0.f,0.f);
        for (int l = lmin; l < 6; ++l){
            float d = fb[O_D1 + (l*12+k)*121 + (m+l)*11 + (p+l)];
            c32 z = zp[(4*l*l*l - l)/3 + (m+l)*(2*l+1) + (p+l)];
            acc.x += d*z.x; acc.y += d*z.y;
        }
        Sc[idx] = acc;
    }
    __syncthreads();
    // Tt[k][mi5][g] = sum_p Sc * e^{+2pi i p g/12}
    for (int idx = tid; idx < 1584; idx += 256){
        int k = idx/132, r = idx%132, mi5 = r/12, g = r%12;
        c32 acc = make_float2(0.f,0.f);
        for (int pi5 = 0; pi5 < 11; ++pi5)
            acc = cadd(acc, cmul(Sc[k*121 + mi5*11 + pi5], tw12[((pi5+55)*g)%12]));
        Tt[idx] = acc;
    }
    __syncthreads();
    // hh[k][a][g] = ReLU( Re sum_m Tt * e^{+2pi i m a/12} + bias )
    for (int idx = tid; idx < 1728; idx += 256){
        int k = idx/144, r = idx%144, a = r/12, g = r%12;
        float s = 0.f;
        for (int mi5 = 0; mi5 < 11; ++mi5){
            c32 t = Tt[k*132 + mi5*12 + g];
            c32 e = tw12[((mi5+55)*a)%12];
            s += t.x*e.x - t.y*e.y;
        }
        s += bias;
        hh[idx] = s > 0.f ? s : 0.f;
    }
    __syncthreads();
    // Gg[k][a][mg] = sum_g hh * e^{-2pi i mg g/12},  mg = 0..2
    for (int idx = tid; idx < 432; idx += 256){
        int k = idx/36, r = idx%36, a = r/3, mg = r%3;
        c32 acc = make_float2(0.f,0.f);
        for (int g = 0; g < 12; ++g){
            c32 e = cconj(tw12[(mg*g)%12]);
            float v = hh[k*144 + a*12 + g];
            acc.x += v*e.x; acc.y += v*e.y;
        }
        Gg[idx] = acc;
    }
    __syncthreads();
    // Gs[k][ma+2][mg] = sum_a Gg * e^{-2pi i ma a/12}, ma = -2..2
    for (int idx = tid; idx < 180; idx += 256){
        int k = idx/15, r = idx%15, mai = r/3, mg = r%3; int ma = mai-2;
        c32 acc = make_float2(0.f,0.f);
        for (int a = 0; a < 12; ++a)
            acc = cadd(acc, cmul(Gg[k*36 + a*3 + mg], cconj(tw12[((ma+60)*a)%12])));
        Gs[idx] = acc;
    }
    __syncthreads();
    // xs2[l][mi][pi] = sum_k G(k, m, p) * SO3D[l][k][mi][pi]   (G(-m,-p)=conj G(m,p))
    if (tid < 35){
        int l = (tid == 0) ? 0 : ((tid < 10) ? 1 : 2);
        int base = (l == 0) ? 0 : ((l == 1) ? 1 : 10);
        int w = 2*l+1, r = tid - base, mi = r/w, pi = r%w;
        int m = mi - l, p = pi - l;
        c32 acc = make_float2(0.f,0.f);
        for (int k = 0; k < 12; ++k){
            float d = fb[O_SO3D + (l*12+k)*25 + mi*5 + pi];
            c32 Gv = (p >= 0) ? Gs[k*15 + (m+2)*3 + p] : cconj(Gs[k*15 + (2-m)*3 + (-p)]);
            acc.x += d*Gv.x; acc.y += d*Gv.y;
        }
        xs2out[(n*8+o)*35 + tid] = acc;
    }
}

// ---------------- layer 2 + integrate: per (n,o) -> feat[n][o] ----------------
__global__ __launch_bounds__(64) void k_layer2(const c32* __restrict__ cb, const float* __restrict__ fb,
                                               const float* __restrict__ b2, float* __restrict__ feat){
    __shared__ c32 xs2_sh[280];
    __shared__ c32 cy2_sh[600];
    __shared__ c32 tw6[6];
    __shared__ c32 zp2[35];
    __shared__ c32 S2sh[150];     // [6][5][5]
    __shared__ c32 T2sh[180];     // [6][5][6]
    int tid = threadIdx.x;
    int n = blockIdx.x >> 4, o = blockIdx.x & 15;
    for (int i = tid; i < 280; i += 64) xs2_sh[i] = cb[O_XS2 + n*280 + i];
    for (int i = tid; i < 600; i += 64) cy2_sh[i] = cb[O_CY2 + o*600 + i];
    if (tid < 6) tw6[tid] = cb[O_TW6 + tid];
    __syncthreads();
    // zp2[l][mi][pi] = (2l+1) sum_{i,qi} xs2[i][l][mi][qi] * cY2[l][i][pi][qi]
    if (tid < 35){
        int l = (tid == 0) ? 0 : ((tid < 10) ? 1 : 2);
        int base = (l == 0) ? 0 : ((l == 1) ? 1 : 10);
        int w = 2*l+1, r = tid - base, mi = r/w, pi = r%w;
        c32 acc = make_float2(0.f,0.f);
        for (int i = 0; i < 8; ++i)
            for (int qi = 0; qi < w; ++qi)
                acc = cadd(acc, cmul(xs2_sh[i*35 + base + mi*w + qi], cy2_sh[(l*8+i)*25 + pi*5 + qi]));
        zp2[tid] = make_float2(w*acc.x, w*acc.y);
    }
    __syncthreads();
    // S2[k][m+2][p+2] = sum_l zp2 * d2
    for (int idx = tid; idx < 150; idx += 64){
        int k = idx/25, r = idx%25, mi = r/5, pi = r%5;
        int m = mi-2, p = pi-2;
        int lmin = max(abs(m), abs(p));
        c32 acc = make_float2(0.f,0.f);
        for (int l = lmin; l < 3; ++l){
            int base = (l == 0) ? 0 : ((l == 1) ? 1 : 10);
            float d = fb[O_D2 + (l*6+k)*25 + (m+l)*5 + (p+l)];
            c32 z = zp2[base + (m+l)*(2*l+1) + (p+l)];
            acc.x += d*z.x; acc.y += d*z.y;
        }
        S2sh[idx] = acc;
    }
    __syncthreads();
    // T2[k][mi][g] = sum_p S2 * e^{+2pi i p g/6}
    for (int idx = tid; idx < 180; idx += 64){
        int k = idx/30, r = idx%30, mi = r/6, g = r%6;
        c32 acc = make_float2(0.f,0.f);
        for (int pi = 0; pi < 5; ++pi)
            acc = cadd(acc, cmul(S2sh[k*25 + mi*5 + pi], tw6[((pi+4)*g)%6]));
        T2sh[idx] = acc;
    }
    __syncthreads();
    // h2, ReLU, integrate
    float bias = b2[o];
    float partial = 0.f;
    for (int idx = tid; idx < 216; idx += 64){
        int k = idx/36, r = idx%36, a = r/6, g = r%6;
        float s = 0.f;
        for (int mi = 0; mi < 5; ++mi){
            c32 t = T2sh[k*30 + mi*6 + g];
            c32 e = tw6[((mi+4)*a)%6];
            s += t.x*e.x - t.y*e.y;
        }
        s += bias;
        if (s > 0.f) partial += s * fb[O_WINT + k];
    }
    for (int off = 32; off; off >>= 1) partial += __shfl_down(partial, off);
    if (tid == 0) feat[n*16 + o] = partial * (1.0f/36.0f);
}

// ---------------- max-pool over 512 points per (b,o) ----------------
__global__ __launch_bounds__(64) void k_pool(const float* __restrict__ feat, float* __restrict__ pool){
    int b = blockIdx.x >> 4, o = blockIdx.x & 15;
    int tid = threadIdx.x;
    float m = -3.4e38f;
    for (int pt = tid; pt < 512; pt += 64)
        m = fmaxf(m, feat[(b*512+pt)*16 + o]);
    for (int off = 32; off; off >>= 1) m = fmaxf(m, __shfl_down(m, off));
    if (tid == 0) pool[b*16 + o] = m;
}

// ---------------- head: out[b][j] = pooled . w_out + bias ----------------
__global__ __launch_bounds__(64) void k_head(const float* __restrict__ pool, const float* __restrict__ w_out,
                                             const float* __restrict__ bias_out, float* __restrict__ out){
    int tid = threadIdx.x;
    if (tid < 40){
        int b = tid/10, j = tid%10;
        float s = bias_out[j];
        for (int o = 0; o < 16; ++o) s += pool[b*16+o]*w_out[j*16+o];
        out[tid] = s;
    }
}

extern "C" void kernel_launch(void* const* d_in, const int* in_sizes, int n_in,
                              void* d_out, int out_size, void* d_ws, size_t ws_size,
                              hipStream_t stream){
    const float* x        = (const float*)d_in[0];
    const float* w1       = (const float*)d_in[1];
    const float* b1       = (const float*)d_in[2];
    const float* w2       = (const float*)d_in[3];
    const float* b2       = (const float*)d_in[4];
    const float* w_out    = (const float*)d_in[5];
    const float* bias_out = (const float*)d_in[6];
    float* out = (float*)d_out;

    c32*   cb = (c32*)d_ws;
    float* fb = (float*)(cb + N_C32_TOTAL);
    float* feat = fb + O_FEAT;
    float* pool = fb + O_POOL;

    k_setup1<<<47, 256, 0, stream>>>(cb, fb);                    // 11857 items
    k_setup2<<<3, 256, 0, stream>>>(cb, fb, w1);                 // 528 items
    k_setup3<<<38, 256, 0, stream>>>(cb, fb, w2);                // 9600 items
    k_s2fft<<<2048, 64, 0, stream>>>(x, cb, fb, cb + O_XS);
    k_layer1<<<2048*8, 256, 0, stream>>>(cb, fb, b1, cb + O_XS2);
    k_layer2<<<2048*16, 64, 0, stream>>>(cb, fb, b2, feat);
    k_pool<<<64, 64, 0, stream>>>(feat, pool);
    k_head<<<1, 64, 0, stream>>>(pool, w_out, bias_out, out);
}

// Round 2
// 223.644 us; speedup vs baseline: 2.2694x; 2.2694x over previous
//
#include <hip/hip_runtime.h>
#include <cmath>

typedef float2 c32;

__device__ __forceinline__ void cmadd(c32& acc, c32 a, float cr, float ci){
    // acc += a * (cr + i*ci)
    acc.x += a.x*cr - a.y*ci;
    acc.y += a.x*ci + a.y*cr;
}

__host__ __device__ constexpr int M12(int x){ return ((x%12)+12)%12; }
__host__ __device__ constexpr int M6(int x){ return ((x%6)+6)%6; }

#define SQ32 0.86602540378443864676f
static constexpr float CW12[12] = {1.f, SQ32, 0.5f, 0.f, -0.5f, -SQ32, -1.f, -SQ32, -0.5f, 0.f, 0.5f, SQ32};
static constexpr float SW12[12] = {0.f, 0.5f, SQ32, 1.f, SQ32, 0.5f, 0.f, -0.5f, -SQ32, -1.f, -SQ32, -0.5f};
static constexpr float CW6[6] = {1.f, 0.5f, -0.5f, -1.f, -0.5f, 0.5f};
static constexpr float SW6[6] = {0.f, SQ32, SQ32, 0.f, -SQ32, -SQ32};

// ---------------- workspace layout ----------------
// float2 region (counts in float2)
#define O_TW20 0
#define O_TW8  20
#define O_TW6  28
#define O_CY1  34                  // [8o][66] : conjY1, (l*11 + p+l)
#define O_CY2P (O_CY1 + 528)       // [16o][22cell][8i][5qt] zero-padded
#define O_XS   (O_CY2P + 14080)    // [2048n][36] : l*l + (m+l)
#define O_XS2P (O_XS + 73728)      // [2048n][8i][30slot] : (lm*5+qt), m>=0 zero-padded
#define N_C32_TOTAL (O_XS2P + 2048*8*30)

// float region
#define O_S2D  0                   // [6l][20k][11mi] : d^l_{m,0}(b_in)*w
#define O_D1SG (O_S2D + 1320)      // [6l][3ib][11pi] : d^l_{p,0}(grid b)
#define O_D2SG (O_D1SG + 198)      // [3l][3ib][5pi][5qi]
#define O_WINT (O_D2SG + 225)      // [6]
#define O_D1S  1752                // [66mp][12k][8lpad] : d^l_{m,p}(b1_k), zero-padded
#define O_DG   (O_D1S + 6336)      // [30slot][12k] : d^l_{m,q}(b1_k)*w6, zero-padded
#define O_D2P  (O_DG + 360)        // [15(m,pi)][6k][4lpad] : d^l_{m,p}(b2_k), zero-padded
#define O_FEAT (O_D2P + 360)       // [2048n][16o]
#define O_POOL (O_FEAT + 32768)    // [4][16]

#define DPI 3.14159265358979323846

// ---------------- Wigner-d on device (double, matches ref float64) ----------------
__device__ __forceinline__ double dev_lf(int n){ return lgamma((double)n + 1.0); }

__device__ double dev_wig(int l, int mp, int m, double beta){
    int k0 = max(0, m - mp), k1 = min(l + m, l - mp);
    double c = cos(0.5*beta), s = sin(0.5*beta);
    double lnum = 0.5*(dev_lf(l+mp)+dev_lf(l-mp)+dev_lf(l+m)+dev_lf(l-m));
    double acc = 0.0;
    for (int k = k0; k <= k1; ++k){
        double lg = lnum - dev_lf(l+m-k) - dev_lf(k) - dev_lf(mp-m+k) - dev_lf(l-mp-k);
        double t = exp(lg) * pow(c, (double)(2*l-2*k+m-mp)) * pow(s, (double)(mp-m+2*k));
        acc += ((mp-m+k) & 1) ? -t : t;
    }
    return acc;
}

__device__ double dev_qw(int b, double beta){
    double s = 0.0;
    for (int j = 0; j < b; ++j) s += sin((2.0*j+1.0)*beta)/(2.0*j+1.0);
    return (2.0/b)*sin(beta)*s;
}

// ---------------- setup 1: weight-independent tables ----------------
__global__ __launch_bounds__(256) void k_setup1(c32* cb, float* fb){
    int gid = blockIdx.x*256 + threadIdx.x;
    if (gid < 20){ double a = -2.0*DPI*gid/20.0; cb[O_TW20+gid] = make_float2((float)cos(a),(float)sin(a)); return; }
    gid -= 20;
    if (gid < 8){ double a =  2.0*DPI*gid/8.0;  cb[O_TW8 +gid] = make_float2((float)cos(a),(float)sin(a)); return; }
    gid -= 8;
    if (gid < 6){ double a =  2.0*DPI*gid/6.0;  cb[O_TW6 +gid] = make_float2((float)cos(a),(float)sin(a)); return; }
    gid -= 6;
    if (gid < 1320){   // S2D
        int mi = gid%11; int t = gid/11; int k = t%20; int l = t/20;
        float v = 0.f;
        if (mi < 2*l+1){
            double beta = DPI*(2*k+1)/40.0;
            v = (float)(dev_wig(l, mi-l, 0, beta) * dev_qw(10, beta));
        }
        fb[O_S2D+gid] = v; return;
    }
    gid -= 1320;
    if (gid < 198){    // D1SG
        int pi = gid%11; int t = gid/11; int ib = t%3; int l = t/3;
        float v = 0.f;
        if (pi < 2*l+1){ double beta = (ib+1)*DPI/24.0; v = (float)dev_wig(l, pi-l, 0, beta); }
        fb[O_D1SG+gid] = v; return;
    }
    gid -= 198;
    if (gid < 225){    // D2SG
        int qi = gid%5; int t = gid/5; int pi = t%5; t /= 5; int ib = t%3; int l = t/3;
        float v = 0.f;
        if (pi < 2*l+1 && qi < 2*l+1){ double beta = (ib+1)*DPI/24.0; v = (float)dev_wig(l, pi-l, qi-l, beta); }
        fb[O_D2SG+gid] = v; return;
    }
    gid -= 225;
    if (gid < 6){ double beta = DPI*(2*gid+1)/12.0; fb[O_WINT+gid] = (float)dev_qw(3, beta); return; }
    gid -= 6;
    if (gid < 6336){   // D1S [66mp][12k][8lp]
        int lp = gid%8; int t = gid/8; int k = t%12; int mp = t/12;
        int m = mp/11, pi = mp%11, p = pi-5, ap = p<0?-p:p;
        float v = 0.f;
        if (lp < 6 && lp >= m && lp >= ap){
            double beta = DPI*(2*k+1)/24.0;
            v = (float)dev_wig(lp, m, p, beta);
        }
        fb[O_D1S+gid] = v; return;
    }
    gid -= 6336;
    if (gid < 360){    // DG [30slot][12k]
        int k = gid%12; int slot = gid/12;
        int lm = slot/5, qt = slot%5;
        int l = lm==0?0:(lm<3?1:2);
        int m = lm==0?0:(lm<3?lm-1:lm-3);
        float v = 0.f;
        if (qt < 2*l+1){
            double beta = DPI*(2*k+1)/24.0;
            v = (float)(dev_wig(l, m, qt-l, beta) * dev_qw(6, beta));
        }
        fb[O_DG+gid] = v; return;
    }
    gid -= 360;
    if (gid < 360){    // D2P [15(m,pi)][6k][4lp]
        int lp = gid%4; int t = gid/4; int k = t%6; int cell = t/6;
        int m = cell/5, pi = cell%5, p = pi-2, ap = p<0?-p:p;
        float v = 0.f;
        if (lp < 3 && lp >= m && lp >= ap){
            double beta = DPI*(2*k+1)/12.0;
            v = (float)dev_wig(lp, m, p, beta);
        }
        fb[O_D2P+gid] = v; return;
    }
}

// ---------------- setup 2: conj(Y1)[o][l][pi] ----------------
__global__ __launch_bounds__(256) void k_setup2(c32* cb, const float* fb, const float* __restrict__ w1){
    int gid = blockIdx.x*256 + threadIdx.x;
    if (gid >= 528) return;
    int pi = gid%11; int t = gid/11; int l = t%6; int o = t/6;
    c32 acc = make_float2(0.f,0.f);
    if (pi < 2*l+1){
        int p = pi - l;
        for (int ib = 0; ib < 3; ++ib){
            float d = fb[O_D1SG + (l*3+ib)*11 + pi];
            c32 s = make_float2(0.f,0.f);
            for (int ia = 0; ia < 8; ++ia){
                c32 e = cb[O_TW8 + ((p+40)*ia)%8];   // e^{+i p alpha}
                float w = w1[o*24 + ib*8 + ia];
                s.x += w*e.x; s.y += w*e.y;
            }
            acc.x += d*s.x; acc.y += d*s.y;
        }
    }
    cb[O_CY1 + (o*6+l)*11 + pi] = acc;
}

// ---------------- setup 3: conj(Y2) padded [o][cell22][i][qt] ----------------
__global__ __launch_bounds__(256) void k_setup3(c32* cb, const float* fb, const float* __restrict__ w2){
    int gid = blockIdx.x*256 + threadIdx.x;
    if (gid >= 14080) return;
    int qt = gid%5; int t = gid/5; int i = t%8; t /= 8; int cell = t%22; int o = t/22;
    int l, p;
    if (cell == 0){ l=0; p=0; }
    else if (cell < 7){ l=1; p=(cell-1)%3 - 1; }
    else { l=2; p=(cell-7)%5 - 2; }
    c32 acc = make_float2(0.f,0.f);
    if (qt < 2*l+1){
        int q = qt - l;
        for (int ib = 0; ib < 3; ++ib){
            float d = fb[O_D2SG + (l*3+ib)*25 + (p+l)*5 + (q+l)];
            c32 s = make_float2(0.f,0.f);
            for (int ia = 0; ia < 8; ++ia){
                c32 e8 = cb[O_TW8 + ((p+40)*ia)%8];
                for (int ig = 0; ig < 6; ++ig){
                    c32 e6 = cb[O_TW6 + ((q+6)*ig)%6];
                    c32 ph = make_float2(e8.x*e6.x - e8.y*e6.y, e8.x*e6.y + e8.y*e6.x);
                    float w = w2[(i*16+o)*144 + ib*48 + ia*6 + ig];
                    s.x += w*ph.x; s.y += w*ph.y;
                }
            }
            acc.x += d*s.x; acc.y += d*s.y;
        }
    }
    cb[O_CY2P + gid] = acc;
}

// ---------------- s2 fft: x[2048,1,20,20] -> XS[n][l^2+mi] ----------------
__global__ __launch_bounds__(64) void k_s2fft(const float* __restrict__ x, const c32* __restrict__ cb,
                                              const float* __restrict__ fb, c32* __restrict__ XS){
    __shared__ float xsh[400];
    __shared__ c32 F1[20][6];
    int n = blockIdx.x, tid = threadIdx.x;
    for (int i = tid; i < 400; i += 64) xsh[i] = x[n*400 + i];
    __syncthreads();
    for (int i = tid; i < 120; i += 64){
        int k = i/6, m = i%6;
        c32 acc = make_float2(0.f,0.f);
        for (int a = 0; a < 20; ++a){
            c32 e = cb[O_TW20 + (m*a)%20];
            float v = xsh[k*20+a];
            acc.x += v*e.x; acc.y += v*e.y;
        }
        F1[k][m] = acc;
    }
    __syncthreads();
    if (tid < 36){
        int l = 0; while ((l+1)*(l+1) <= tid) ++l;
        int mi = tid - l*l; int m = mi - l;
        c32 acc = make_float2(0.f,0.f);
        for (int k = 0; k < 20; ++k){
            float d = fb[O_S2D + (l*20+k)*11 + mi];
            c32 F = (m >= 0) ? F1[k][m] : make_float2(F1[k][-m].x, -F1[k][-m].y);
            acc.x += d*F.x; acc.y += d*F.y;
        }
        XS[n*36 + tid] = acc;
    }
}

// ---------------- layer 1 megakernel: per (n,o), Hermitian-halved ----------------
__global__ __launch_bounds__(256) void k_layer1(const c32* __restrict__ cb, const float* __restrict__ fb,
                                                const float* __restrict__ b1, c32* __restrict__ xs2p){
    __shared__ c32 xs_sh[36];
    __shared__ c32 u1[864];   // zps[6][66] -> T[6m][12g][12k]
    __shared__ c32 u2[864];   // S[66mp][12k] -> h float[12a][12g][12k]
    __shared__ c32 Gg[432];   // [3mg][12a][12k]
    __shared__ c32 Gs[180];   // [5mai][3mg][12k]
    int tid = threadIdx.x;
    int n = blockIdx.x >> 3, o = blockIdx.x & 7;
    float bias = b1[o];
    if (tid < 36) xs_sh[tid] = cb[O_XS + n*36 + tid];
    __syncthreads();

    // A: zps[l][mp] = (2l+1) * xs_l(m) * conjY1_l(p), m>=0, zero-padded
    for (int c = tid; c < 396; c += 256){
        int l = c/66, mp = c - l*66, m = mp/11, pi = mp - m*11;
        int p = pi - 5, ap = p < 0 ? -p : p;
        c32 v = make_float2(0.f, 0.f);
        if (m <= l && ap <= l){
            c32 a = xs_sh[l*l + l + m];
            c32 b = cb[O_CY1 + o*66 + l*11 + p + l];
            float f = (float)(2*l+1);
            v.x = f*(a.x*b.x - a.y*b.y); v.y = f*(a.x*b.y + a.y*b.x);
        }
        u1[c] = v;
    }
    __syncthreads();

    // B: S[mp][k] = sum_l d1s * zps   (d zero-padded)
    for (int c = tid; c < 792; c += 256){
        int mp = c/12, k = c - mp*12;
        const float4* dp = reinterpret_cast<const float4*>(fb + O_D1S + (mp*12+k)*8);
        float4 da = dp[0], db = dp[1];
        float dl[6] = {da.x, da.y, da.z, da.w, db.x, db.y};
        c32 acc = make_float2(0.f,0.f);
        #pragma unroll
        for (int l = 0; l < 6; ++l){
            c32 z = u1[l*66 + mp];
            acc.x += dl[l]*z.x; acc.y += dl[l]*z.y;
        }
        u2[mp*12 + k] = acc;
    }
    __syncthreads();

    // C: T[m][g][k] = sum_p S ω12^{pg}, radix even/odd-g split; m=0..5 only
    {
        int par = tid >> 7, r = tid & 127;
        if (r < 72){
            int m = r/12, k = r - m*12;
            c32 sv[11];
            #pragma unroll
            for (int pi = 0; pi < 11; ++pi) sv[pi] = u2[(m*11+pi)*12 + k];
            c32 cf[6];
            if (par == 0){
                #pragma unroll
                for (int j = 0; j < 5; ++j) cf[j] = make_float2(sv[j].x+sv[j+6].x, sv[j].y+sv[j+6].y);
                cf[5] = sv[5];
                #pragma unroll
                for (int gi = 0; gi < 6; ++gi){
                    const int g = 2*gi;
                    c32 t = make_float2(0.f,0.f);
                    #pragma unroll
                    for (int j = 0; j < 6; ++j){
                        const int tt = M12((j-5)*g);
                        cmadd(t, cf[j], CW12[tt], SW12[tt]);
                    }
                    u1[(m*12+g)*12 + k] = t;
                }
            } else {
                #pragma unroll
                for (int j = 0; j < 5; ++j) cf[j] = make_float2(sv[j].x-sv[j+6].x, sv[j].y-sv[j+6].y);
                cf[5] = sv[5];
                #pragma unroll
                for (int gi = 0; gi < 6; ++gi){
                    const int g = 2*gi+1;
                    c32 t = make_float2(0.f,0.f);
                    #pragma unroll
                    for (int j = 0; j < 6; ++j){
                        const int tt = M12((j-5)*g);
                        cmadd(t, cf[j], CW12[tt], SW12[tt]);
                    }
                    u1[(m*12+g)*12 + k] = t;
                }
            }
        }
    }
    __syncthreads();

    // D: h[a][g][k] = ReLU( T0 + 2*sum_{m>0} Re(Tm ω12^{ma}) + bias ), even/odd-a shared
    float* hh = (float*)u2;
    if (tid < 144){
        int g = tid/12, k = tid - g*12;
        c32 t1 = u1[(1*12+g)*12+k], t2 = u1[(2*12+g)*12+k], t3 = u1[(3*12+g)*12+k];
        c32 t4 = u1[(4*12+g)*12+k], t5 = u1[(5*12+g)*12+k];
        float base = u1[(0*12+g)*12+k].x + bias;
        #pragma unroll
        for (int a = 0; a < 6; ++a){
            float od = t1.x*CW12[M12(1*a)] - t1.y*SW12[M12(1*a)]
                     + t3.x*CW12[M12(3*a)] - t3.y*SW12[M12(3*a)]
                     + t5.x*CW12[M12(5*a)] - t5.y*SW12[M12(5*a)];
            float ev = t2.x*CW12[M12(2*a)] - t2.y*SW12[M12(2*a)]
                     + t4.x*CW12[M12(4*a)] - t4.y*SW12[M12(4*a)];
            float h0 = base + 2.f*(ev+od);
            float h1 = base + 2.f*(ev-od);
            hh[(a*12+g)*12+k]     = h0 > 0.f ? h0 : 0.f;
            hh[((a+6)*12+g)*12+k] = h1 > 0.f ? h1 : 0.f;
        }
    }
    __syncthreads();

    // E: Gg[mg][a][k] = sum_g h * e^{-2πi mg g/12}, mg=0..2
    if (tid < 144){
        int a = tid/12, k = tid - a*12;
        float hv[12];
        #pragma unroll
        for (int g = 0; g < 12; ++g) hv[g] = hh[(a*12+g)*12+k];
        #pragma unroll
        for (int mg = 0; mg < 3; ++mg){
            float ax = 0.f, ay = 0.f;
            #pragma unroll
            for (int g = 0; g < 12; ++g){
                const int tt = M12(mg*g);
                ax += hv[g]*CW12[tt]; ay -= hv[g]*SW12[tt];
            }
            Gg[(mg*12+a)*12+k] = make_float2(ax, ay);
        }
    }
    __syncthreads();

    // F: Gs[mai][mg][k] = sum_a Gg * e^{-2πi ma a/12}, ma=-2..2
    if (tid < 36){
        int mg = tid/12, k = tid - mg*12;
        c32 gv[12];
        #pragma unroll
        for (int a = 0; a < 12; ++a) gv[a] = Gg[(mg*12+a)*12+k];
        #pragma unroll
        for (int mai = 0; mai < 5; ++mai){
            const int ma = mai - 2;
            c32 acc = make_float2(0.f,0.f);
            #pragma unroll
            for (int a = 0; a < 12; ++a){
                const int tt = M12(-ma*a);
                cmadd(acc, gv[a], CW12[tt], SW12[tt]);
            }
            Gs[(mai*3+mg)*12+k] = acc;
        }
    }
    __syncthreads();

    // G: xs2p slot(lm,qt): sum_k dG * G(k,m,q), G(-m,-q)=conj G(m,q). Zero-padded output.
    if (tid < 30){
        int lm = tid/5, qt = tid - lm*5;
        int l = lm==0?0:(lm<3?1:2);
        int m = lm==0?0:(lm<3?lm-1:lm-3);
        c32 acc = make_float2(0.f,0.f);
        if (qt < 2*l+1){
            int q = qt - l;
            #pragma unroll
            for (int k = 0; k < 12; ++k){
                float d = fb[O_DG + tid*12 + k];
                c32 gvv;
                if (q >= 0) gvv = Gs[((m+2)*3 + q)*12 + k];
                else { c32 w = Gs[((2-m)*3 + (-q))*12 + k]; gvv = make_float2(w.x, -w.y); }
                acc.x += d*gvv.x; acc.y += d*gvv.y;
            }
        }
        xs2p[(n*8+o)*30 + tid] = acc;
    }
}

// ---------------- layer 2 + integrate: block per n, all 16 o ----------------
__global__ __launch_bounds__(256) void k_layer2(const c32* __restrict__ cb, const float* __restrict__ fb,
                                                const float* __restrict__ b2, float* __restrict__ feat){
    __shared__ c32 xs2sh[240];    // [8i][6lm][5qt]
    __shared__ c32 zp2[384];      // [16o][24cellpad]
    __shared__ c32 T2[1728];      // [16o][6k][3m][6g]
    __shared__ float part[576];   // [16o][36(k,g)]
    int tid = threadIdx.x, n = blockIdx.x;
    if (tid < 240) xs2sh[tid] = cb[O_XS2P + n*240 + tid];
    __syncthreads();

    // Z: z2[o][cell] = (2l+1) sum_{i,q} xs2(i,l,m,q) cY2(o,l,i,p,q)  (m>=0 cells)
    for (int c = tid; c < 352; c += 256){
        int o = c/22, cell = c - o*22;
        int l, lm;
        if (cell == 0){ l=0; lm=0; }
        else if (cell < 7){ l=1; lm=1+(cell-1)/3; }
        else { l=2; lm=3+(cell-7)/5; }
        const c32* cy = cb + O_CY2P + (o*22+cell)*40;
        c32 acc = make_float2(0.f,0.f);
        #pragma unroll
        for (int i = 0; i < 8; ++i){
            #pragma unroll
            for (int qt = 0; qt < 5; ++qt){
                c32 xv = xs2sh[(i*6+lm)*5 + qt];
                c32 yv = cy[i*5+qt];
                acc.x += xv.x*yv.x - xv.y*yv.y;
                acc.y += xv.x*yv.y + xv.y*yv.x;
            }
        }
        float f = (float)(2*l+1);
        zp2[o*24+cell] = make_float2(f*acc.x, f*acc.y);
    }
    __syncthreads();

    // ST: S2(p) = sum_l d2*z2 (m>=0), then T2[m][g] = sum_p S2 ω6^{pg}
    for (int c = tid; c < 288; c += 256){
        int o = c/18, r = c - o*18, k = r/3, m = r - k*3;
        c32 s2v[5];
        #pragma unroll
        for (int pi = 0; pi < 5; ++pi){
            const int p = pi-2; const int ap = p<0?-p:p;
            c32 acc = make_float2(0.f,0.f);
            #pragma unroll
            for (int l = 0; l < 3; ++l){
                if (l >= ap){
                    float d = fb[O_D2P + ((m*5+pi)*6+k)*4 + l];  // 0 if l<m
                    int cell = (l==0) ? 0 : ((l==1) ? 1+m*3+(p+1) : 7+m*5+(p+2));
                    c32 z = zp2[o*24+cell];
                    acc.x += d*z.x; acc.y += d*z.y;
                }
            }
            s2v[pi] = acc;
        }
        #pragma unroll
        for (int g = 0; g < 6; ++g){
            c32 t = make_float2(0.f,0.f);
            #pragma unroll
            for (int pi = 0; pi < 5; ++pi){
                const int tt = M6((pi-2)*g);
                cmadd(t, s2v[pi], CW6[tt], SW6[tt]);
            }
            T2[((o*6+k)*3+m)*6+g] = t;
        }
    }
    __syncthreads();

    // H: h2 = T0 + 2*sum_{m=1,2} Re(Tm ω6^{ma}) + bias; relu; integrate
    for (int c = tid; c < 576; c += 256){
        int o = c/36, r = c - o*36, k = r/6, g = r - k*6;
        c32 t0 = T2[((o*6+k)*3+0)*6+g];
        c32 t1 = T2[((o*6+k)*3+1)*6+g];
        c32 t2 = T2[((o*6+k)*3+2)*6+g];
        float base = t0.x + b2[o];
        float s = 0.f;
        #pragma unroll
        for (int a = 0; a < 6; ++a){
            float h = base + 2.f*(t1.x*CW6[M6(a)]   - t1.y*SW6[M6(a)])
                           + 2.f*(t2.x*CW6[M6(2*a)] - t2.y*SW6[M6(2*a)]);
            s += h > 0.f ? h : 0.f;
        }
        part[c] = s * fb[O_WINT + k];
    }
    __syncthreads();
    if (tid < 16){
        float s = 0.f;
        #pragma unroll
        for (int j = 0; j < 36; ++j) s += part[tid*36+j];
        feat[n*16+tid] = s * (1.f/36.f);
    }
}

// ---------------- max-pool over 512 points per (b,o) ----------------
__global__ __launch_bounds__(64) void k_pool(const float* __restrict__ feat, float* __restrict__ pool){
    int b = blockIdx.x >> 4, o = blockIdx.x & 15;
    int tid = threadIdx.x;
    float m = -3.4e38f;
    for (int pt = tid; pt < 512; pt += 64)
        m = fmaxf(m, feat[(b*512+pt)*16 + o]);
    for (int off = 32; off; off >>= 1) m = fmaxf(m, __shfl_down(m, off));
    if (tid == 0) pool[b*16 + o] = m;
}

// ---------------- head ----------------
__global__ __launch_bounds__(64) void k_head(const float* __restrict__ pool, const float* __restrict__ w_out,
                                             const float* __restrict__ bias_out, float* __restrict__ out){
    int tid = threadIdx.x;
    if (tid < 40){
        int b = tid/10, j = tid%10;
        float s = bias_out[j];
        for (int o = 0; o < 16; ++o) s += pool[b*16+o]*w_out[j*16+o];
        out[tid] = s;
    }
}

extern "C" void kernel_launch(void* const* d_in, const int* in_sizes, int n_in,
                              void* d_out, int out_size, void* d_ws, size_t ws_size,
                              hipStream_t stream){
    const float* x        = (const float*)d_in[0];
    const float* w1       = (const float*)d_in[1];
    const float* b1       = (const float*)d_in[2];
    const float* w2       = (const float*)d_in[3];
    const float* b2       = (const float*)d_in[4];
    const float* w_out    = (const float*)d_in[5];
    const float* bias_out = (const float*)d_in[6];
    float* out = (float*)d_out;

    c32*   cb = (c32*)d_ws;
    float* fb = (float*)(cb + N_C32_TOTAL);
    float* feat = fb + O_FEAT;
    float* pool = fb + O_POOL;

    k_setup1<<<35, 256, 0, stream>>>(cb, fb);                    // 8839 items
    k_setup2<<<3, 256, 0, stream>>>(cb, fb, w1);                 // 528 items
    k_setup3<<<55, 256, 0, stream>>>(cb, fb, w2);                // 14080 items
    k_s2fft<<<2048, 64, 0, stream>>>(x, cb, fb, cb + O_XS);
    k_layer1<<<2048*8, 256, 0, stream>>>(cb, fb, b1, cb + O_XS2P);
    k_layer2<<<2048, 256, 0, stream>>>(cb, fb, b2, feat);
    k_pool<<<64, 64, 0, stream>>>(feat, pool);
    k_head<<<1, 64, 0, stream>>>(pool, w_out, bias_out, out);
}

// Round 4
// 186.483 us; speedup vs baseline: 2.7216x; 1.1993x over previous
//
#include <hip/hip_runtime.h>
#include <cmath>

typedef float2 c32;

__device__ __forceinline__ void cmadd(c32& acc, c32 a, float cr, float ci){
    acc.x += a.x*cr - a.y*ci;
    acc.y += a.x*ci + a.y*cr;
}

__host__ __device__ constexpr int M12(int x){ return ((x%12)+12)%12; }
__host__ __device__ constexpr int M6(int x){ return ((x%6)+6)%6; }

#define SQ32 0.86602540378443864676f
#define RT22 0.70710678118654752440f
static constexpr float CW12[12] = {1.f, SQ32, 0.5f, 0.f, -0.5f, -SQ32, -1.f, -SQ32, -0.5f, 0.f, 0.5f, SQ32};
static constexpr float SW12[12] = {0.f, 0.5f, SQ32, 1.f, SQ32, 0.5f, 0.f, -0.5f, -SQ32, -1.f, -SQ32, -0.5f};
static constexpr float CW6[6] = {1.f, 0.5f, -0.5f, -1.f, -0.5f, 0.5f};
static constexpr float SW6[6] = {0.f, SQ32, SQ32, 0.f, -SQ32, -SQ32};
static constexpr float CW8[8] = {1.f, RT22, 0.f, -RT22, -1.f, -RT22, 0.f, RT22};
static constexpr float SW8[8] = {0.f, RT22, 1.f, RT22, 0.f, -RT22, -1.f, -RT22};
static constexpr float CW20_[6] = {1.f, 0.95105651629515357212f, 0.80901699437494742410f,
                                   0.58778525229247312917f, 0.30901699437494742410f, 0.f};
static constexpr float SW20_[6] = {0.f, 0.30901699437494742410f, 0.58778525229247312917f,
                                   0.80901699437494742410f, 0.95105651629515357212f, 1.f};

// ---------------- workspace layout ----------------
// float2 region
#define O_CY1  0                   // [8o][66]
#define O_CY2P 528                 // [16o][22cell][8i][5qt]
#define O_XS   (O_CY2P + 14080)    // [2048n][36]
#define O_XS2P (O_XS + 73728)      // [2048n][8i][30slot]
#define N_C32_TOTAL (O_XS2P + 2048*8*30)

// float region
#define O_S2D  0                   // [6l][20k][11mi]
#define O_D1SG 1320                // [6l][3ib][11pi]
#define O_D2SG 1518                // [3l][3ib][5pi][5qi]
#define O_WINT 1743                // [6]
#define O_D1S  1752                // [66mp][12k][8lpad]
#define O_DG   (O_D1S + 6336)      // [30slot][12k]
#define O_D2P  (O_DG + 360)        // [15(m,pi)][6k][4lpad]
#define O_FEAT (O_D2P + 360)       // [2048n][16o]
#define O_POOL (O_FEAT + 32768)    // [4][16]

#define DPI 3.14159265358979323846

// ---------------- Wigner-d via factorial table (no lgamma/pow/exp) ----------------
static constexpr double FCT[13] = {1.,1.,2.,6.,24.,120.,720.,5040.,40320.,
                                   362880.,3628800.,39916800.,479001600.};

__device__ __forceinline__ double dipow(double b, int e){
    double r = 1.0;
    while (e){ if (e & 1) r *= b; b *= b; e >>= 1; }
    return r;
}

__device__ double dev_wig(int l, int mp, int m, double beta){
    int k0 = max(0, m - mp), k1 = min(l + m, l - mp);
    double c = cos(0.5*beta), s = sin(0.5*beta);
    double fnum = sqrt(FCT[l+mp]*FCT[l-mp]*FCT[l+m]*FCT[l-m]);
    double acc = 0.0;
    for (int k = k0; k <= k1; ++k){
        double t = fnum / (FCT[l+m-k]*FCT[k]*FCT[mp-m+k]*FCT[l-mp-k])
                 * dipow(c, 2*l-2*k+m-mp) * dipow(s, mp-m+2*k);
        acc += ((mp-m+k) & 1) ? -t : t;
    }
    return acc;
}

__device__ double dev_qw(int b, double beta){
    double s = 0.0;
    for (int j = 0; j < b; ++j) s += sin((2.0*j+1.0)*beta)/(2.0*j+1.0);
    return (2.0/b)*sin(beta)*s;
}

// ---------------- setup 1: weight-independent tables ----------------
__global__ __launch_bounds__(256) void k_setup1(c32* cb, float* fb){
    int gid = blockIdx.x*256 + threadIdx.x;
    if (gid < 1320){   // S2D
        int mi = gid%11; int t = gid/11; int k = t%20; int l = t/20;
        float v = 0.f;
        if (mi < 2*l+1){
            double beta = DPI*(2*k+1)/40.0;
            v = (float)(dev_wig(l, mi-l, 0, beta) * dev_qw(10, beta));
        }
        fb[O_S2D+gid] = v; return;
    }
    gid -= 1320;
    if (gid < 198){    // D1SG
        int pi = gid%11; int t = gid/11; int ib = t%3; int l = t/3;
        float v = 0.f;
        if (pi < 2*l+1){ double beta = (ib+1)*DPI/24.0; v = (float)dev_wig(l, pi-l, 0, beta); }
        fb[O_D1SG+gid] = v; return;
    }
    gid -= 198;
    if (gid < 225){    // D2SG
        int qi = gid%5; int t = gid/5; int pi = t%5; t /= 5; int ib = t%3; int l = t/3;
        float v = 0.f;
        if (pi < 2*l+1 && qi < 2*l+1){ double beta = (ib+1)*DPI/24.0; v = (float)dev_wig(l, pi-l, qi-l, beta); }
        fb[O_D2SG+gid] = v; return;
    }
    gid -= 225;
    if (gid < 6){ double beta = DPI*(2*gid+1)/12.0; fb[O_WINT+gid] = (float)dev_qw(3, beta); return; }
    gid -= 6;
    if (gid < 6336){   // D1S [66mp][12k][8lp]
        int lp = gid%8; int t = gid/8; int k = t%12; int mp = t/12;
        int m = mp/11, pi = mp%11, p = pi-5, ap = p<0?-p:p;
        float v = 0.f;
        if (lp < 6 && lp >= m && lp >= ap){
            double beta = DPI*(2*k+1)/24.0;
            v = (float)dev_wig(lp, m, p, beta);
        }
        fb[O_D1S+gid] = v; return;
    }
    gid -= 6336;
    if (gid < 360){    // DG [30slot][12k]
        int k = gid%12; int slot = gid/12;
        int lm = slot/5, qt = slot%5;
        int l = lm==0?0:(lm<3?1:2);
        int m = lm==0?0:(lm<3?lm-1:lm-3);
        float v = 0.f;
        if (qt < 2*l+1){
            double beta = DPI*(2*k+1)/24.0;
            v = (float)(dev_wig(l, m, qt-l, beta) * dev_qw(6, beta));
        }
        fb[O_DG+gid] = v; return;
    }
    gid -= 360;
    if (gid < 360){    // D2P [15(m,pi)][6k][4lp]
        int lp = gid%4; int t = gid/4; int k = t%6; int cell = t/6;
        int m = cell/5, pi = cell%5, p = pi-2, ap = p<0?-p:p;
        float v = 0.f;
        if (lp < 3 && lp >= m && lp >= ap){
            double beta = DPI*(2*k+1)/12.0;
            v = (float)dev_wig(lp, m, p, beta);
        }
        fb[O_D2P+gid] = v; return;
    }
}

// ---------------- setup 2: conj(Y1)[o][l][pi] ----------------
__global__ __launch_bounds__(256) void k_setup2(c32* cb, const float* fb, const float* __restrict__ w1){
    int gid = blockIdx.x*256 + threadIdx.x;
    if (gid >= 528) return;
    int pi = gid%11; int t = gid/11; int l = t%6; int o = t/6;
    c32 acc = make_float2(0.f,0.f);
    if (pi < 2*l+1){
        int p = pi - l;
        int pm = ((p%8)+8)%8;
        float wr = CW8[pm], wi = SW8[pm];    // e^{+2pi i p/8}
        for (int ib = 0; ib < 3; ++ib){
            float d = fb[O_D1SG + (l*3+ib)*11 + pi];
            float er = 1.f, ei = 0.f, sx = 0.f, sy = 0.f;
            #pragma unroll
            for (int ia = 0; ia < 8; ++ia){
                float w = w1[o*24 + ib*8 + ia];
                sx += w*er; sy += w*ei;
                float nr = er*wr - ei*wi; ei = er*wi + ei*wr; er = nr;
            }
            acc.x += d*sx; acc.y += d*sy;
        }
    }
    cb[O_CY1 + (o*6+l)*11 + pi] = acc;
}

// ---------------- setup 3: conj(Y2), separable DFT, block per (o,i) ----------------
__global__ __launch_bounds__(64) void k_setup3(c32* cb, const float* fb, const float* __restrict__ w2){
    __shared__ float wsh[144];
    __shared__ c32 W1[3][8][5];
    __shared__ c32 R[3][5][5];
    int bo = blockIdx.x;          // o*8 + i
    int o = bo >> 3, i = bo & 7;
    int tid = threadIdx.x;
    for (int c = tid; c < 144; c += 64) wsh[c] = w2[(i*16+o)*144 + c];
    __syncthreads();
    // W1[ib][ia][qi] = sum_ig w * e^{+2pi i q ig/6}
    for (int c = tid; c < 120; c += 64){
        int ib = c/40, r = c%40, ia = r/5, qi = r%5;
        int q = qi - 2; int qm = ((q%6)+6)%6;
        float wr = CW6[qm], wi = SW6[qm];
        float er = 1.f, ei = 0.f, sx = 0.f, sy = 0.f;
        const float* wrow = wsh + ib*48 + ia*6;
        #pragma unroll
        for (int ig = 0; ig < 6; ++ig){
            float w = wrow[ig];
            sx += w*er; sy += w*ei;
            float nr = er*wr - ei*wi; ei = er*wi + ei*wr; er = nr;
        }
        W1[ib][ia][qi] = make_float2(sx, sy);
    }
    __syncthreads();
    // R[ib][pi][qi] = sum_ia W1 * e^{+2pi i p ia/8}
    for (int c = tid; c < 75; c += 64){
        int ib = c/25, r = c%25, pi = r/5, qi = r%5;
        int p = pi - 2; int pm = ((p%8)+8)%8;
        float wr = CW8[pm], wi = SW8[pm];
        float er = 1.f, ei = 0.f;
        c32 acc = make_float2(0.f,0.f);
        #pragma unroll
        for (int ia = 0; ia < 8; ++ia){
            c32 wv = W1[ib][ia][qi];
            acc.x += wv.x*er - wv.y*ei;
            acc.y += wv.x*ei + wv.y*er;
            float nr = er*wr - ei*wi; ei = er*wi + ei*wr; er = nr;
        }
        R[ib][pi][qi] = acc;
    }
    __syncthreads();
    // combine with d, write zero-padded CY2P cells
    for (int c = tid; c < 110; c += 64){
        int cell = c/5, qt = c%5;
        int l, p;
        if (cell == 0){ l=0; p=0; }
        else if (cell < 7){ l=1; p=(cell-1)%3 - 1; }
        else { l=2; p=(cell-7)%5 - 2; }
        c32 acc = make_float2(0.f,0.f);
        if (qt < 2*l+1){
            int q = qt - l;
            #pragma unroll
            for (int ib = 0; ib < 3; ++ib){
                float d = fb[O_D2SG + (l*3+ib)*25 + (p+l)*5 + (q+l)];
                c32 rv = R[ib][p+2][q+2];
                acc.x += d*rv.x; acc.y += d*rv.y;
            }
        }
        cb[O_CY2P + ((o*22+cell)*8 + i)*5 + qt] = acc;
    }
}

// ---------------- s2 fft: x[2048,1,20,20] -> XS[n][l^2+mi] ----------------
__global__ __launch_bounds__(64) void k_s2fft(const float* __restrict__ x, const float* __restrict__ fb,
                                              c32* __restrict__ XS){
    __shared__ float xsh[400];
    __shared__ c32 F1[20][6];
    int n = blockIdx.x, tid = threadIdx.x;
    for (int i = tid; i < 400; i += 64) xsh[i] = x[n*400 + i];
    __syncthreads();
    for (int i = tid; i < 120; i += 64){
        int k = i/6, m = i%6;
        float wr = CW20_[m], wi = -SW20_[m];   // e^{-2pi i m/20}
        float er = 1.f, ei = 0.f, ax = 0.f, ay = 0.f;
        const float* row = xsh + k*20;
        #pragma unroll
        for (int a = 0; a < 20; ++a){
            float v = row[a];
            ax += v*er; ay += v*ei;
            float nr = er*wr - ei*wi; ei = er*wi + ei*wr; er = nr;
        }
        F1[k][m] = make_float2(ax, ay);
    }
    __syncthreads();
    if (tid < 36){
        int l = 0; while ((l+1)*(l+1) <= tid) ++l;
        int mi = tid - l*l; int m = mi - l;
        c32 acc = make_float2(0.f,0.f);
        for (int k = 0; k < 20; ++k){
            float d = fb[O_S2D + (l*20+k)*11 + mi];
            c32 F = (m >= 0) ? F1[k][m] : make_float2(F1[k][-m].x, -F1[k][-m].y);
            acc.x += d*F.x; acc.y += d*F.y;
        }
        XS[n*36 + tid] = acc;
    }
}

// ---------------- layer 1 megakernel: per (n,o), Hermitian-halved ----------------
__global__ __launch_bounds__(256) void k_layer1(const c32* __restrict__ cb, const float* __restrict__ fb,
                                                const float* __restrict__ b1, c32* __restrict__ xs2p){
    __shared__ c32 xs_sh[36];
    __shared__ c32 u1[864];   // zps[6][66] -> T[6m][12g][12k]
    __shared__ c32 u2[936];   // S[66mp][12k] -> h float[12a][12g][13kpad]
    __shared__ c32 Gg[432];   // [3mg][12a][12k]
    __shared__ c32 Gs[180];   // [5mai][3mg][12k]
    int tid = threadIdx.x;
    int n = blockIdx.x >> 3, o = blockIdx.x & 7;
    float bias = b1[o];
    if (tid < 36) xs_sh[tid] = cb[O_XS + n*36 + tid];
    __syncthreads();

    // A: zps[l][mp] = (2l+1) * xs_l(m) * conjY1_l(p), m>=0, zero-padded
    for (int c = tid; c < 396; c += 256){
        int l = c/66, mp = c - l*66, m = mp/11, pi = mp - m*11;
        int p = pi - 5, ap = p < 0 ? -p : p;
        c32 v = make_float2(0.f, 0.f);
        if (m <= l && ap <= l){
            c32 a = xs_sh[l*l + l + m];
            c32 b = cb[O_CY1 + o*66 + l*11 + p + l];
            float f = (float)(2*l+1);
            v.x = f*(a.x*b.x - a.y*b.y); v.y = f*(a.x*b.y + a.y*b.x);
        }
        u1[c] = v;
    }
    __syncthreads();

    // B: S[mp][k] = sum_l d1s * zps
    for (int c = tid; c < 792; c += 256){
        int mp = c/12, k = c - mp*12;
        const float4* dp = reinterpret_cast<const float4*>(fb + O_D1S + (mp*12+k)*8);
        float4 da = dp[0], db = dp[1];
        float dl[6] = {da.x, da.y, da.z, da.w, db.x, db.y};
        c32 acc = make_float2(0.f,0.f);
        #pragma unroll
        for (int l = 0; l < 6; ++l){
            c32 z = u1[l*66 + mp];
            acc.x += dl[l]*z.x; acc.y += dl[l]*z.y;
        }
        u2[mp*12 + k] = acc;
    }
    __syncthreads();

    // C: T[m][g][k] = sum_p S w12^{pg}, radix even/odd-g split
    {
        int par = tid >> 7, r = tid & 127;
        if (r < 72){
            int m = r/12, k = r - m*12;
            c32 sv[11];
            #pragma unroll
            for (int pi = 0; pi < 11; ++pi) sv[pi] = u2[(m*11+pi)*12 + k];
            c32 cf[6];
            if (par == 0){
                #pragma unroll
                for (int j = 0; j < 5; ++j) cf[j] = make_float2(sv[j].x+sv[j+6].x, sv[j].y+sv[j+6].y);
                cf[5] = sv[5];
                #pragma unroll
                for (int gi = 0; gi < 6; ++gi){
                    const int g = 2*gi;
                    c32 t = make_float2(0.f,0.f);
                    #pragma unroll
                    for (int j = 0; j < 6; ++j){
                        const int tt = M12((j-5)*g);
                        cmadd(t, cf[j], CW12[tt], SW12[tt]);
                    }
                    u1[(m*12+g)*12 + k] = t;
                }
            } else {
                #pragma unroll
                for (int j = 0; j < 5; ++j) cf[j] = make_float2(sv[j].x-sv[j+6].x, sv[j].y-sv[j+6].y);
                cf[5] = sv[5];
                #pragma unroll
                for (int gi = 0; gi < 6; ++gi){
                    const int g = 2*gi+1;
                    c32 t = make_float2(0.f,0.f);
                    #pragma unroll
                    for (int j = 0; j < 6; ++j){
                        const int tt = M12((j-5)*g);
                        cmadd(t, cf[j], CW12[tt], SW12[tt]);
                    }
                    u1[(m*12+g)*12 + k] = t;
                }
            }
        }
    }
    __syncthreads();

    // D: h[a][g][k] = ReLU( T0 + 2*sum_{m>0} Re(Tm w12^{ma}) + bias ), k-stride 13
    float* hh = (float*)u2;
    if (tid < 144){
        int g = tid/12, k = tid - g*12;
        c32 t1 = u1[(1*12+g)*12+k], t2 = u1[(2*12+g)*12+k], t3 = u1[(3*12+g)*12+k];
        c32 t4 = u1[(4*12+g)*12+k], t5 = u1[(5*12+g)*12+k];
        float base = u1[(0*12+g)*12+k].x + bias;
        #pragma unroll
        for (int a = 0; a < 6; ++a){
            float od = t1.x*CW12[M12(1*a)] - t1.y*SW12[M12(1*a)]
                     + t3.x*CW12[M12(3*a)] - t3.y*SW12[M12(3*a)]
                     + t5.x*CW12[M12(5*a)] - t5.y*SW12[M12(5*a)];
            float ev = t2.x*CW12[M12(2*a)] - t2.y*SW12[M12(2*a)]
                     + t4.x*CW12[M12(4*a)] - t4.y*SW12[M12(4*a)];
            float h0 = base + 2.f*(ev+od);
            float h1 = base + 2.f*(ev-od);
            hh[(a*12+g)*13+k]     = h0 > 0.f ? h0 : 0.f;
            hh[((a+6)*12+g)*13+k] = h1 > 0.f ? h1 : 0.f;
        }
    }
    __syncthreads();

    // E: Gg[mg][a][k] = sum_g h * e^{-2pi i mg g/12}, mg=0 special-cased (real)
    if (tid < 144){
        int a = tid/12, k = tid - a*12;
        float hv[12];
        #pragma unroll
        for (int g = 0; g < 12; ++g) hv[g] = hh[(a*12+g)*13+k];
        float s0 = 0.f;
        #pragma unroll
        for (int g = 0; g < 12; ++g) s0 += hv[g];
        Gg[a*12+k] = make_float2(s0, 0.f);
        #pragma unroll
        for (int mg = 1; mg < 3; ++mg){
            float ax = 0.f, ay = 0.f;
            #pragma unroll
            for (int g = 0; g < 12; ++g){
                const int tt = M12(mg*g);
                ax += hv[g]*CW12[tt]; ay -= hv[g]*SW12[tt];
            }
            Gg[(mg*12+a)*12+k] = make_float2(ax, ay);
        }
    }
    __syncthreads();

    // F: Gs[mai][mg][k] = sum_a Gg * e^{-2pi i ma a/12}; 180 lanes, rotation twiddle
    if (tid < 180){
        int mai = tid/36, r = tid - mai*36, mg = r/12, k = r - mg*12;
        int sm = M12(-(mai-2));
        float wr = CW12[sm], wi = SW12[sm];
        float er = 1.f, ei = 0.f;
        c32 acc = make_float2(0.f,0.f);
        #pragma unroll
        for (int a = 0; a < 12; ++a){
            c32 gvv = Gg[(mg*12+a)*12+k];
            acc.x += gvv.x*er - gvv.y*ei;
            acc.y += gvv.x*ei + gvv.y*er;
            float nr = er*wr - ei*wi; ei = er*wi + ei*wr; er = nr;
        }
        Gs[(mai*3+mg)*12+k] = acc;
    }
    __syncthreads();

    // G: xs2p slot(lm,qt): sum_k dG * G(k,m,q)
    if (tid < 30){
        int lm = tid/5, qt = tid - lm*5;
        int l = lm==0?0:(lm<3?1:2);
        int m = lm==0?0:(lm<3?lm-1:lm-3);
        c32 acc = make_float2(0.f,0.f);
        if (qt < 2*l+1){
            int q = qt - l;
            #pragma unroll
            for (int k = 0; k < 12; ++k){
                float d = fb[O_DG + tid*12 + k];
                c32 gvv;
                if (q >= 0) gvv = Gs[((m+2)*3 + q)*12 + k];
                else { c32 w = Gs[((2-m)*3 + (-q))*12 + k]; gvv = make_float2(w.x, -w.y); }
                acc.x += d*gvv.x; acc.y += d*gvv.y;
            }
        }
        xs2p[(n*8+o)*30 + tid] = acc;
    }
}

// ---------------- layer 2 + integrate: block per 4 n, all 16 o ----------------
__global__ __launch_bounds__(256) void k_layer2(const c32* __restrict__ cb, const float* __restrict__ fb,
                                                const float* __restrict__ b2, float* __restrict__ feat){
    __shared__ c32 xs2sh[960];    // [4nl][8i][6lm][5qt]
    __shared__ c32 zp2[4][384];   // [nl][16o][24cellpad]
    __shared__ c32 T2[1728];      // [16o][6k][3m][6g], reused per nl
    __shared__ float part[576];   // [16o][36(k,g)]
    int tid = threadIdx.x, n0 = blockIdx.x*4;
    for (int c = tid; c < 960; c += 256) xs2sh[c] = cb[O_XS2P + n0*240 + c];
    __syncthreads();

    // Z for all 4 n
    for (int c = tid; c < 1408; c += 256){
        int nl = c/352, cc = c - nl*352, o = cc/22, cell = cc - o*22;
        int l, lm;
        if (cell == 0){ l=0; lm=0; }
        else if (cell < 7){ l=1; lm=1+(cell-1)/3; }
        else { l=2; lm=3+(cell-7)/5; }
        const c32* cy = cb + O_CY2P + (o*22+cell)*40;
        const c32* xv0 = xs2sh + nl*240;
        c32 acc = make_float2(0.f,0.f);
        #pragma unroll
        for (int i = 0; i < 8; ++i){
            #pragma unroll
            for (int qt = 0; qt < 5; ++qt){
                c32 xv = xv0[(i*6+lm)*5 + qt];
                c32 yv = cy[i*5+qt];
                acc.x += xv.x*yv.x - xv.y*yv.y;
                acc.y += xv.x*yv.y + xv.y*yv.x;
            }
        }
        float f = (float)(2*l+1);
        zp2[nl][o*24+cell] = make_float2(f*acc.x, f*acc.y);
    }
    __syncthreads();

    for (int nl = 0; nl < 4; ++nl){
        // ST: S2(p) = sum_l d2*z2, then T2[m][g] = sum_p S2 w6^{pg}
        for (int c = tid; c < 288; c += 256){
            int o = c/18, r = c - o*18, k = r/3, m = r - k*3;
            c32 s2v[5];
            #pragma unroll
            for (int pi = 0; pi < 5; ++pi){
                const int p = pi-2; const int ap = p<0?-p:p;
                c32 acc = make_float2(0.f,0.f);
                #pragma unroll
                for (int l = 0; l < 3; ++l){
                    if (l >= ap){
                        float d = fb[O_D2P + ((m*5+pi)*6+k)*4 + l];   // 0 if l<m
                        int cell = (l==0) ? 0 : ((l==1) ? 1+m*3+(p+1) : 7+m*5+(p+2));
                        c32 z = zp2[nl][o*24+cell];
                        acc.x += d*z.x; acc.y += d*z.y;
                    }
                }
                s2v[pi] = acc;
            }
            #pragma unroll
            for (int g = 0; g < 6; ++g){
                c32 t = make_float2(0.f,0.f);
                #pragma unroll
                for (int pi = 0; pi < 5; ++pi){
                    const int tt = M6((pi-2)*g);
                    cmadd(t, s2v[pi], CW6[tt], SW6[tt]);
                }
                T2[((o*6+k)*3+m)*6+g] = t;
            }
        }
        __syncthreads();
        // H: h2 = T0 + 2*sum_{m=1,2} Re(Tm w6^{ma}) + bias; relu; integrate
        for (int c = tid; c < 576; c += 256){
            int o = c/36, r = c - o*36, k = r/6, g = r - k*6;
            c32 t0 = T2[((o*6+k)*3+0)*6+g];
            c32 t1 = T2[((o*6+k)*3+1)*6+g];
            c32 t2 = T2[((o*6+k)*3+2)*6+g];
            float base = t0.x + b2[o];
            float s = 0.f;
            #pragma unroll
            for (int a = 0; a < 6; ++a){
                float h = base + 2.f*(t1.x*CW6[M6(a)]   - t1.y*SW6[M6(a)])
                               + 2.f*(t2.x*CW6[M6(2*a)] - t2.y*SW6[M6(2*a)]);
                s += h > 0.f ? h : 0.f;
            }
            part[c] = s * fb[O_WINT + k];
        }
        __syncthreads();
        if (tid < 16){
            float s = 0.f;
            #pragma unroll
            for (int j = 0; j < 36; ++j) s += part[tid*36+j];
            feat[(n0+nl)*16+tid] = s * (1.f/36.f);
        }
        __syncthreads();
    }
}

// ---------------- max-pool over 512 points per (b,o) ----------------
__global__ __launch_bounds__(64) void k_pool(const float* __restrict__ feat, float* __restrict__ pool){
    int b = blockIdx.x >> 4, o = blockIdx.x & 15;
    int tid = threadIdx.x;
    float m = -3.4e38f;
    for (int pt = tid; pt < 512; pt += 64)
        m = fmaxf(m, feat[(b*512+pt)*16 + o]);
    for (int off = 32; off; off >>= 1) m = fmaxf(m, __shfl_down(m, off));
    if (tid == 0) pool[b*16 + o] = m;
}

// ---------------- head ----------------
__global__ __launch_bounds__(64) void k_head(const float* __restrict__ pool, const float* __restrict__ w_out,
                                             const float* __restrict__ bias_out, float* __restrict__ out){
    int tid = threadIdx.x;
    if (tid < 40){
        int b = tid/10, j = tid%10;
        float s = bias_out[j];
        for (int o = 0; o < 16; ++o) s += pool[b*16+o]*w_out[j*16+o];
        out[tid] = s;
    }
}

extern "C" void kernel_launch(void* const* d_in, const int* in_sizes, int n_in,
                              void* d_out, int out_size, void* d_ws, size_t ws_size,
                              hipStream_t stream){
    const float* x        = (const float*)d_in[0];
    const float* w1       = (const float*)d_in[1];
    const float* b1       = (const float*)d_in[2];
    const float* w2       = (const float*)d_in[3];
    const float* b2       = (const float*)d_in[4];
    const float* w_out    = (const float*)d_in[5];
    const float* bias_out = (const float*)d_in[6];
    float* out = (float*)d_out;

    c32*   cb = (c32*)d_ws;
    float* fb = (float*)(cb + N_C32_TOTAL);
    float* feat = fb + O_FEAT;
    float* pool = fb + O_POOL;

    k_setup1<<<35, 256, 0, stream>>>(cb, fb);                    // 8805 items
    k_setup2<<<3, 256, 0, stream>>>(cb, fb, w1);                 // 528 items
    k_setup3<<<128, 64, 0, stream>>>(cb, fb, w2);                // block per (o,i)
    k_s2fft<<<2048, 64, 0, stream>>>(x, fb, cb + O_XS);
    k_layer1<<<2048*8, 256, 0, stream>>>(cb, fb, b1, cb + O_XS2P);
    k_layer2<<<512, 256, 0, stream>>>(cb, fb, b2, feat);
    k_pool<<<64, 64, 0, stream>>>(feat, pool);
    k_head<<<1, 64, 0, stream>>>(pool, w_out, bias_out, out);
}